// Round 3
// baseline (1599.248 us; speedup 1.0000x reference)
//
#include <hip/hip_runtime.h>
#include <hip/hip_bf16.h>

// Flow-matching MLP ODE, 32 midpoint-t Euler steps.
// R3: 16x16x32 MFMA (16 batch cols/wave) to halve per-wave register state ->
// 1024-thr blocks, 4 waves/SIMD at <=128 VGPR (was 2 waves/SIMD, reg-bound).
// Weights as A-frags; activations as B-frags; batch col = lane&15 stays
// lane-resident; C->B via v_cvt_pk_bf16_f32 + permlane32_swap + permlane16_swap.
// W2+W1 frags in LDS (160KB); biases (as A-frag k-rows x [t,1] B-frag) + W3
// from global (L2-resident). fp32 accum + fp32 x state.

typedef __attribute__((ext_vector_type(8)))  short s16x8;   // 8 bf16 (4 VGPR)
typedef __attribute__((ext_vector_type(4)))  float f32x4;   // 16x16 MFMA acc

union FragU { s16x8 v; unsigned u[4]; };

__device__ __forceinline__ unsigned cvtpk_bf16(float lo, float hi){
  unsigned r;
  asm("v_cvt_pk_bf16_f32 %0, %1, %2" : "=v"(r) : "v"(lo), "v"(hi));
  return r;
}
__device__ __forceinline__ void plswap32(unsigned &a, unsigned &b){
  // a'[l>=32]=b[l-32]; b'[l<32]=a[l+32]
  asm("v_permlane32_swap_b32 %0, %1" : "+v"(a), "+v"(b));
}
__device__ __forceinline__ void plswap16(unsigned &a, unsigned &b){
  // within each 32: a'[g1]=b[g0], b'[g0]=a[g1] (and g3/g2)
  asm("v_permlane16_swap_b32 %0, %1" : "+v"(a), "+v"(b));
}

// Two 16-feature C tiles (C layout: col=l&15, row=4*(l>>4)+i) -> one K=32
// B-frag of the next layer (slot (g,j): k=8g+j, feature F2+k).
// u[0]=[A0,A2,B0,B2], u[2]=[A1,A3,B1,B3] (Ai = pk(rows 4i,4i+1) at group i).
__device__ __forceinline__ s16x8 c16_to_b(const f32x4 cA, const f32x4 cB){
  unsigned a0 = cvtpk_bf16(cA[0], cA[1]);
  unsigned a1 = cvtpk_bf16(cA[2], cA[3]);
  unsigned b0 = cvtpk_bf16(cB[0], cB[1]);
  unsigned b1 = cvtpk_bf16(cB[2], cB[3]);
  plswap32(a0, b0); plswap16(a0, b0);
  plswap32(a1, b1); plswap16(a1, b1);
  FragU r; r.u[0]=a0; r.u[1]=a1; r.u[2]=b0; r.u[3]=b1; return r.v;
}

__device__ __forceinline__ f32x4 silu4(f32x4 x){
#pragma unroll
  for (int i = 0; i < 4; i++){
    float e = __builtin_amdgcn_exp2f(x[i] * -1.44269504088896f); // exp(-x)
    x[i] = x[i] * __builtin_amdgcn_rcpf(1.0f + e);
  }
  return x;
}

// ---- setup: pack weights + bias frags (bf16 16x32 A-fragment images) ----
// frag(Mt,Kt): lane l holds W[Kt*32 + 8*(l>>4)+j][Mt*16 + (l&15)], j=0..7
// ws shorts: [0,65536) W2 (Mt*8+Kt). [65536,81920) W1 (Mt*2+Kt).
// [81920,98304) W3 (Mt*8+Kt). [98304,106496) t1A (k0=t-row,k1=b1).
// [106496,114688) b2A (k0=b2). [114688,116736) b3A (k0=b3).
__global__ void setup_kernel(const float* __restrict__ W1,
                             const float* __restrict__ b1,
                             const float* __restrict__ W2,
                             const float* __restrict__ b2,
                             const float* __restrict__ W3,
                             const float* __restrict__ b3,
                             short* __restrict__ ws){
  const int f = blockIdx.x;
  const int l = threadIdx.x;
  const int g = l >> 4, col = l & 15;

  if (f < 192){
    const float* src; int N, Mt, Kt; short* dst;
    if (f < 128)      { Mt = f >> 3;      Kt = f & 7; src = W2; N = 256; dst = ws + f*512; }
    else if (f < 160) { int id = f - 128; Mt = id >> 1; Kt = id & 1; src = W1; N = 256; dst = ws + 65536 + id*512; }
    else              { int id = f - 160; Mt = id >> 3; Kt = id & 7; src = W3; N = 64;  dst = ws + 81920 + id*512; }
#pragma unroll
    for (int j = 0; j < 8; j++){
      const int k = Kt*32 + 8*g + j;
      const int n = Mt*16 + col;
      float v = src[(size_t)k * N + n];
      __hip_bfloat16 h = __float2bfloat16(v);
      dst[l*8 + j] = *reinterpret_cast<short*>(&h);
    }
  } else {
    short* dst; int Mt, kind;
    if (f < 208)      { kind = 0; Mt = f - 192; dst = ws + 98304  + Mt*512; }
    else if (f < 224) { kind = 1; Mt = f - 208; dst = ws + 106496 + Mt*512; }
    else              { kind = 2; Mt = f - 224; dst = ws + 114688 + Mt*512; }
    const int n = Mt*16 + col;
#pragma unroll
    for (int j = 0; j < 8; j++){
      const int k = 8*g + j;
      float v = 0.0f;
      if (kind == 0){
        if (k == 0) v = W1[(size_t)64*256 + n];   // t-coefficient row
        else if (k == 1) v = b1[n];
      } else if (kind == 1){
        if (k == 0) v = b2[n];
      } else {
        if (k == 0) v = b3[n];
      }
      __hip_bfloat16 h = __float2bfloat16(v);
      dst[l*8 + j] = *reinterpret_cast<short*>(&h);
    }
  }
}

__launch_bounds__(1024, 4)
__global__ void flow_kernel(const float* __restrict__ x0,
                            const short* __restrict__ ws,
                            float* __restrict__ out){
  extern __shared__ short lds[];   // 160 KiB: W2 [0,65536), W1 [65536,81920)
  const int tid = threadIdx.x;
  {
    const int4* src = (const int4*)ws;
    int4* dst = (int4*)lds;
#pragma unroll
    for (int i = 0; i < 10; i++) dst[tid + i*1024] = src[tid + i*1024];
  }
  __syncthreads();

  const short* w2l = lds;
  const short* w1l = lds + 65536;
  const short* w3f = ws + 81920;
  const short* t1g = ws + 98304;
  const short* b2g = ws + 106496;
  const short* b3g = ws + 114688;

  const int lane = tid & 63;
  const int wv   = tid >> 6;
  const int g    = lane >> 4;
  const int c    = lane & 15;
  const int lf   = lane * 8;
  const float dt = 1.0f / 32.0f;

  s16x8 onef;   // B-frag [1,0,...]: k=0 -> 1.0
  { FragU o; o.u[0] = (g==0) ? 0x00003F80u : 0u; o.u[1]=0u; o.u[2]=0u; o.u[3]=0u; onef = o.v; }
  const f32x4 zf = {0.f, 0.f, 0.f, 0.f};

  for (int pass = 0; pass < 2; pass++){
    const int row = blockIdx.x*512 + pass*256 + wv*16 + c;
    const float* xin = x0 + (size_t)row * 64;

    // x state: xr[T][i] = x[row][16T + 4g + i]  (C layout per 16-dim tile)
    f32x4 xr[4];
#pragma unroll
    for (int T = 0; T < 4; T++) xr[T] = *(const f32x4*)(xin + T*16 + g*4);

    s16x8 b1f[2];
    b1f[0] = c16_to_b(xr[0], xr[1]);
    b1f[1] = c16_to_b(xr[2], xr[3]);

#pragma unroll 1
    for (int s = 0; s < 32; s++){
      const float tv = ((float)s + 0.5f) * (1.0f / 32.0f);
      s16x8 tf;   // B-frag [t,1,0...]: k=0 -> t, k=1 -> 1
      { FragU o; o.u[0] = (g==0) ? cvtpk_bf16(tv, 1.0f) : 0u; o.u[1]=0u; o.u[2]=0u; o.u[3]=0u; tf = o.v; }

      // ---- layer 1: h1 = silu(x@W1x + t*W1t + b1); bias via t1A x tf ----
      s16x8 b2f[8];
#pragma unroll
      for (int p = 0; p < 8; p++){
        f32x4 aA = __builtin_amdgcn_mfma_f32_16x16x32_bf16(
                     *(const s16x8*)(t1g + (2*p  )*512 + lf), tf, zf, 0, 0, 0);
        f32x4 aB = __builtin_amdgcn_mfma_f32_16x16x32_bf16(
                     *(const s16x8*)(t1g + (2*p+1)*512 + lf), tf, zf, 0, 0, 0);
#pragma unroll
        for (int kt = 0; kt < 2; kt++){
          aA = __builtin_amdgcn_mfma_f32_16x16x32_bf16(
                 *(const s16x8*)(w1l + ((2*p  )*2 + kt)*512 + lf), b1f[kt], aA, 0, 0, 0);
          aB = __builtin_amdgcn_mfma_f32_16x16x32_bf16(
                 *(const s16x8*)(w1l + ((2*p+1)*2 + kt)*512 + lf), b1f[kt], aB, 0, 0, 0);
        }
        b2f[p] = c16_to_b(silu4(aA), silu4(aB));
      }

      // ---- layer 2 (+fused layer 3): v = silu(h1@W2+b2)@W3 + b3 ----
      f32x4 c3[4];
#pragma unroll
      for (int T = 0; T < 4; T++)
        c3[T] = __builtin_amdgcn_mfma_f32_16x16x32_bf16(
                  *(const s16x8*)(b3g + T*512 + lf), onef, zf, 0, 0, 0);
#pragma unroll
      for (int p = 0; p < 8; p++){
        f32x4 aA = __builtin_amdgcn_mfma_f32_16x16x32_bf16(
                     *(const s16x8*)(b2g + (2*p  )*512 + lf), onef, zf, 0, 0, 0);
        f32x4 aB = __builtin_amdgcn_mfma_f32_16x16x32_bf16(
                     *(const s16x8*)(b2g + (2*p+1)*512 + lf), onef, zf, 0, 0, 0);
#pragma unroll
        for (int kt = 0; kt < 8; kt++){
          aA = __builtin_amdgcn_mfma_f32_16x16x32_bf16(
                 *(const s16x8*)(w2l + ((2*p  )*8 + kt)*512 + lf), b2f[kt], aA, 0, 0, 0);
          aB = __builtin_amdgcn_mfma_f32_16x16x32_bf16(
                 *(const s16x8*)(w2l + ((2*p+1)*8 + kt)*512 + lf), b2f[kt], aB, 0, 0, 0);
        }
        s16x8 pf = c16_to_b(silu4(aA), silu4(aB));   // layer-3 K-frag p
#pragma unroll
        for (int T = 0; T < 4; T++)
          c3[T] = __builtin_amdgcn_mfma_f32_16x16x32_bf16(
                    *(const s16x8*)(w3f + (T*8 + p)*512 + lf), pf, c3[T], 0, 0, 0);
      }

      // ---- x += dt*v ; rebuild x B-frags ----
#pragma unroll
      for (int T = 0; T < 4; T++)
#pragma unroll
        for (int i = 0; i < 4; i++) xr[T][i] += dt * c3[T][i];
      b1f[0] = c16_to_b(xr[0], xr[1]);
      b1f[1] = c16_to_b(xr[2], xr[3]);
    }

    float* xo = out + (size_t)row * 64;
#pragma unroll
    for (int T = 0; T < 4; T++) *(f32x4*)(xo + T*16 + g*4) = xr[T];
  }
}

extern "C" void kernel_launch(void* const* d_in, const int* in_sizes, int n_in,
                              void* d_out, int out_size, void* d_ws, size_t ws_size,
                              hipStream_t stream){
  const float* x0 = (const float*)d_in[0];
  const float* W1 = (const float*)d_in[1];
  const float* b1 = (const float*)d_in[2];
  const float* W2 = (const float*)d_in[3];
  const float* b2 = (const float*)d_in[4];
  const float* W3 = (const float*)d_in[5];
  const float* b3 = (const float*)d_in[6];
  short* ws  = (short*)d_ws;
  float* out = (float*)d_out;
  (void)in_sizes; (void)n_in; (void)out_size; (void)ws_size;

  hipFuncSetAttribute((const void*)flow_kernel,
                      hipFuncAttributeMaxDynamicSharedMemorySize, 163840);

  setup_kernel<<<228, 64, 0, stream>>>(W1, b1, W2, b2, W3, b3, ws);
  flow_kernel<<<256, 1024, 163840, stream>>>(x0, ws, out);
}

// Round 5
// 1102.654 us; speedup vs baseline: 1.4504x; 1.4504x over previous
//
#include <hip/hip_runtime.h>
#include <hip/hip_bf16.h>

// Flow-matching MLP ODE, 32 midpoint-t Euler steps.
// R5 = R2 structure (32x32x16 MFMA, 32 batch rows/wave, W1+W2 frags in 160KB
// LDS, 512-thr blocks) + verified fixes only:
//  1. amdgpu_waves_per_eu(2,2): unlock 256-reg budget (R2's 128-VGPR squeeze
//     forced AGPR round-trips; LDS caps occupancy at 2 waves/SIMD anyway).
//  2. Dual accumulator chains (aA/aB) in layer1/layer2: halve dependent-MFMA
//     latency stall; scheduler interleaves the pair + silu.
//  3. Layer-2/3 accumulators init from direct fp32 C-layout loads of b2/b3
//     (R1-proven pattern) -- removes 10 chain-head MFMAs/step and 32 live regs.
// No hand-written packed-f32 asm (R4's NaN suspect); no uninit prefetch regs.

typedef __attribute__((ext_vector_type(8)))  short s16x8;   // 8 bf16 (4 VGPR)
typedef __attribute__((ext_vector_type(16))) float f32x16;  // MFMA acc
typedef __attribute__((ext_vector_type(4)))  float f32x4;

union FragU { s16x8 v; unsigned u[4]; };

__device__ __forceinline__ unsigned cvtpk_bf16(float lo, float hi){
  unsigned r;
  asm("v_cvt_pk_bf16_f32 %0, %1, %2" : "=v"(r) : "v"(lo), "v"(hi));
  return r;
}
__device__ __forceinline__ void plswap32(unsigned &a, unsigned &b){
  asm("v_permlane32_swap_b32 %0, %1" : "+v"(a), "+v"(b));
}

// C-tile (acc layout n=(r&3)+8*(r>>2)+4*g, m=l&31) -> two next-layer B-frags.
__device__ __forceinline__ void c_to_b(const f32x16 c, s16x8 &f0, s16x8 &f1){
  unsigned p0 = cvtpk_bf16(c[0],  c[1]);
  unsigned p1 = cvtpk_bf16(c[2],  c[3]);
  unsigned p2 = cvtpk_bf16(c[4],  c[5]);
  unsigned p3 = cvtpk_bf16(c[6],  c[7]);
  plswap32(p0, p2); plswap32(p1, p3);
  FragU a; a.u[0]=p0; a.u[1]=p1; a.u[2]=p2; a.u[3]=p3; f0 = a.v;
  unsigned q0 = cvtpk_bf16(c[8],  c[9]);
  unsigned q1 = cvtpk_bf16(c[10], c[11]);
  unsigned q2 = cvtpk_bf16(c[12], c[13]);
  plswap32(q0, q2);
  unsigned q1b = cvtpk_bf16(c[14], c[15]);
  plswap32(q1, q1b);
  FragU b; b.u[0]=q0; b.u[1]=q1; b.u[2]=q2; b.u[3]=q1b; f1 = b.v;
}

__device__ __forceinline__ void silu16(f32x16 &x){
#pragma unroll
  for (int i = 0; i < 16; i++){
    float e = __builtin_amdgcn_exp2f(x[i] * -1.44269504088896f); // exp(-x)
    x[i] = x[i] * __builtin_amdgcn_rcpf(1.0f + e);
  }
}

// ---- setup: pack weights + t1 frags (bf16 A-fragment images) into d_ws ----
// frag(Mt,Kt): lane l holds WT[Mt*32 + (l&31)][Kt*16 + 8*(l>>5) + j], j=0..7
// ws shorts: [0,65536) W2 frags. [65536,81920) W1. [81920,98304) W3.
//            [98304,102400) t1-frags (k0=W1[64] t-row, k1=b1).
__global__ void setup_kernel(const float* __restrict__ W1,
                             const float* __restrict__ b1,
                             const float* __restrict__ W2,
                             const float* __restrict__ W3,
                             short* __restrict__ ws){
  const int f = blockIdx.x;
  const int l = threadIdx.x;
  const int g = l >> 5, col = l & 31;

  if (f < 192){
    const float* src; int N, Mt, Kt; short* dst;
    if (f < 128)      { Mt = f >> 4;      Kt = f & 15;       src = W2; N = 256; dst = ws + f*512; }
    else if (f < 160) { int id = f - 128; Mt = id >> 2; Kt = id & 3;  src = W1; N = 256; dst = ws + 65536 + id*512; }
    else              { int id = f - 160; Mt = id >> 4; Kt = id & 15; src = W3; N = 64;  dst = ws + 81920 + id*512; }
#pragma unroll
    for (int j = 0; j < 8; j++){
      const int k = Kt*16 + 8*g + j;
      const int n = Mt*32 + col;
      float v = src[(size_t)k * N + n];
      __hip_bfloat16 h = __float2bfloat16(v);
      dst[l*8 + j] = *reinterpret_cast<short*>(&h);
    }
  } else {
    const int Mt = f - 192;
    short* dst = ws + 98304 + Mt*512;
    const int n = Mt*32 + col;
#pragma unroll
    for (int j = 0; j < 8; j++){
      const int k = 8*g + j;
      float v = 0.0f;
      if (k == 0) v = W1[(size_t)64*256 + n];   // t-coefficient row
      else if (k == 1) v = b1[n];
      __hip_bfloat16 h = __float2bfloat16(v);
      dst[l*8 + j] = *reinterpret_cast<short*>(&h);
    }
  }
}

__global__ __launch_bounds__(512) __attribute__((amdgpu_waves_per_eu(2, 2)))
void flow_kernel(const float* __restrict__ x0,
                 const short* __restrict__ ws,
                 const float* __restrict__ b2,
                 const float* __restrict__ b3,
                 float* __restrict__ out){
  extern __shared__ short lds[];   // 160 KiB: W2 [0,65536), W1 [65536,81920)
  const int tid = threadIdx.x;
  {
    const int4* src = (const int4*)ws;
    int4* dst = (int4*)lds;
#pragma unroll
    for (int i = 0; i < 20; i++) dst[tid + i*512] = src[tid + i*512];
  }
  __syncthreads();

  const short* w2l = lds;
  const short* w1l = lds + 65536;
  const short* w3f = ws + 81920;
  const short* t1g = ws + 98304;

  const int lane = tid & 63;
  const int wv   = tid >> 6;
  const int g    = lane >> 5;
  const int m    = lane & 31;
  const int lf   = lane * 8;
  const float dt = 1.0f / 32.0f;

  const f32x16 zf = {0.f,0.f,0.f,0.f,0.f,0.f,0.f,0.f,0.f,0.f,0.f,0.f,0.f,0.f,0.f,0.f};

  for (int pass = 0; pass < 2; pass++){
    const int rowbase = blockIdx.x * 512 + (wv*2 + pass) * 32;
    const float* xin = x0 + (size_t)(rowbase + m) * 64;

    // x state in C layout: xr[t][4q+i] = x[row m][32t + 8q + 4g + i]
    f32x16 xr[2];
#pragma unroll
    for (int t = 0; t < 2; t++)
#pragma unroll
      for (int q = 0; q < 4; q++){
        f32x4 v = *(const f32x4*)(xin + t*32 + q*8 + g*4);
#pragma unroll
        for (int i = 0; i < 4; i++) xr[t][q*4+i] = v[i];
      }

    s16x8 b1f[4];
    c_to_b(xr[0], b1f[0], b1f[1]);
    c_to_b(xr[1], b1f[2], b1f[3]);

#pragma unroll 1
    for (int s = 0; s < 32; s++){
      const float tv = ((float)s + 0.5f) * (1.0f / 32.0f);
      s16x8 tf;   // B-frag [t,1,0...]
      { FragU o; o.u[0] = (g==0) ? cvtpk_bf16(tv, 1.0f) : 0u; o.u[1]=0u; o.u[2]=0u; o.u[3]=0u; tf = o.v; }

      // ---- layer 1: h1 = silu(x@W1x + t*W1t + b1); bias via t1f x tf ----
      s16x8 b2f[16];
#pragma unroll
      for (int mp = 0; mp < 4; mp++){
        const int MtA = 2*mp, MtB = 2*mp + 1;
        s16x8 t1a = *(const s16x8*)(t1g + MtA*512 + lf);
        s16x8 t1b = *(const s16x8*)(t1g + MtB*512 + lf);
        f32x16 aA = __builtin_amdgcn_mfma_f32_32x32x16_bf16(t1a, tf, zf, 0, 0, 0);
        f32x16 aB = __builtin_amdgcn_mfma_f32_32x32x16_bf16(t1b, tf, zf, 0, 0, 0);
#pragma unroll
        for (int kt = 0; kt < 4; kt++){
          aA = __builtin_amdgcn_mfma_f32_32x32x16_bf16(
                 *(const s16x8*)(w1l + (MtA*4 + kt)*512 + lf), b1f[kt], aA, 0, 0, 0);
          aB = __builtin_amdgcn_mfma_f32_32x32x16_bf16(
                 *(const s16x8*)(w1l + (MtB*4 + kt)*512 + lf), b1f[kt], aB, 0, 0, 0);
        }
        silu16(aA); silu16(aB);
        c_to_b(aA, b2f[2*MtA], b2f[2*MtA+1]);
        c_to_b(aB, b2f[2*MtB], b2f[2*MtB+1]);
      }

      // ---- c3 init from b3 (fp32 C-layout loads, L1-hot) ----
      f32x16 c3[2];
#pragma unroll
      for (int t3 = 0; t3 < 2; t3++)
#pragma unroll
        for (int q = 0; q < 4; q++){
          f32x4 bv = *(const f32x4*)(b3 + t3*32 + q*8 + g*4);
#pragma unroll
          for (int i = 0; i < 4; i++) c3[t3][q*4+i] = bv[i];
        }

      // ---- layer 2 (+fused layer 3): v = silu(h1@W2+b2)@W3 + b3 ----
#pragma unroll
      for (int mp = 0; mp < 4; mp++){
        const int MtA = 2*mp, MtB = 2*mp + 1;
        s16x8 w3aA = *(const s16x8*)(w3f + (2*MtA    )*512 + lf);
        s16x8 w3bA = *(const s16x8*)(w3f + (2*MtA + 1)*512 + lf);
        s16x8 w3cA = *(const s16x8*)(w3f + (16 + 2*MtA)*512 + lf);
        s16x8 w3dA = *(const s16x8*)(w3f + (17 + 2*MtA)*512 + lf);
        s16x8 w3aB = *(const s16x8*)(w3f + (2*MtB    )*512 + lf);
        s16x8 w3bB = *(const s16x8*)(w3f + (2*MtB + 1)*512 + lf);
        s16x8 w3cB = *(const s16x8*)(w3f + (16 + 2*MtB)*512 + lf);
        s16x8 w3dB = *(const s16x8*)(w3f + (17 + 2*MtB)*512 + lf);

        // acc init from b2 (fp32 C-layout loads)
        f32x16 aA, aB;
#pragma unroll
        for (int q = 0; q < 4; q++){
          f32x4 bvA = *(const f32x4*)(b2 + MtA*32 + q*8 + g*4);
          f32x4 bvB = *(const f32x4*)(b2 + MtB*32 + q*8 + g*4);
#pragma unroll
          for (int i = 0; i < 4; i++){ aA[q*4+i] = bvA[i]; aB[q*4+i] = bvB[i]; }
        }
#pragma unroll
        for (int kt = 0; kt < 16; kt++){
          aA = __builtin_amdgcn_mfma_f32_32x32x16_bf16(
                 *(const s16x8*)(w2l + (MtA*16 + kt)*512 + lf), b2f[kt], aA, 0, 0, 0);
          aB = __builtin_amdgcn_mfma_f32_32x32x16_bf16(
                 *(const s16x8*)(w2l + (MtB*16 + kt)*512 + lf), b2f[kt], aB, 0, 0, 0);
        }
        silu16(aA); silu16(aB);
        s16x8 f0A, f1A, f0B, f1B;
        c_to_b(aA, f0A, f1A);
        c_to_b(aB, f0B, f1B);
        c3[0] = __builtin_amdgcn_mfma_f32_32x32x16_bf16(w3aA, f0A, c3[0], 0, 0, 0);
        c3[1] = __builtin_amdgcn_mfma_f32_32x32x16_bf16(w3cA, f0A, c3[1], 0, 0, 0);
        c3[0] = __builtin_amdgcn_mfma_f32_32x32x16_bf16(w3bA, f1A, c3[0], 0, 0, 0);
        c3[1] = __builtin_amdgcn_mfma_f32_32x32x16_bf16(w3dA, f1A, c3[1], 0, 0, 0);
        c3[0] = __builtin_amdgcn_mfma_f32_32x32x16_bf16(w3aB, f0B, c3[0], 0, 0, 0);
        c3[1] = __builtin_amdgcn_mfma_f32_32x32x16_bf16(w3cB, f0B, c3[1], 0, 0, 0);
        c3[0] = __builtin_amdgcn_mfma_f32_32x32x16_bf16(w3bB, f1B, c3[0], 0, 0, 0);
        c3[1] = __builtin_amdgcn_mfma_f32_32x32x16_bf16(w3dB, f1B, c3[1], 0, 0, 0);
      }

      // ---- x += dt*v ; rebuild x B-frags ----
#pragma unroll
      for (int t = 0; t < 2; t++)
#pragma unroll
        for (int i = 0; i < 16; i++) xr[t][i] += dt * c3[t][i];
      c_to_b(xr[0], b1f[0], b1f[1]);
      c_to_b(xr[1], b1f[2], b1f[3]);
    }

    float* xo = out + (size_t)(rowbase + m) * 64;
#pragma unroll
    for (int t = 0; t < 2; t++)
#pragma unroll
      for (int q = 0; q < 4; q++){
        f32x4 v;
#pragma unroll
        for (int i = 0; i < 4; i++) v[i] = xr[t][q*4+i];
        *(f32x4*)(xo + t*32 + q*8 + g*4) = v;
      }
  }
}

extern "C" void kernel_launch(void* const* d_in, const int* in_sizes, int n_in,
                              void* d_out, int out_size, void* d_ws, size_t ws_size,
                              hipStream_t stream){
  const float* x0 = (const float*)d_in[0];
  const float* W1 = (const float*)d_in[1];
  const float* b1 = (const float*)d_in[2];
  const float* W2 = (const float*)d_in[3];
  const float* b2 = (const float*)d_in[4];
  const float* W3 = (const float*)d_in[5];
  const float* b3 = (const float*)d_in[6];
  short* ws  = (short*)d_ws;
  float* out = (float*)d_out;
  (void)in_sizes; (void)n_in; (void)out_size; (void)ws_size;

  hipFuncSetAttribute((const void*)flow_kernel,
                      hipFuncAttributeMaxDynamicSharedMemorySize, 163840);

  setup_kernel<<<200, 64, 0, stream>>>(W1, b1, W2, W3, ws);
  flow_kernel<<<256, 512, 163840, stream>>>(x0, ws, b2, b3, out);
}